// Round 2
// baseline (1047.433 us; speedup 1.0000x reference)
//
#include <hip/hip_runtime.h>
#include <cstdint>
#include <cstddef>

#define AS1 __attribute__((address_space(1)))
#define AS3 __attribute__((address_space(3)))

typedef __attribute__((ext_vector_type(8))) __bf16 bf16x8;
typedef __attribute__((ext_vector_type(4))) float f32x4;

__device__ __forceinline__ void gload_lds16(const void* g, void* l) {
  __builtin_amdgcn_global_load_lds((AS1 void*)g, (AS3 void*)l, 16, 0, 0);
}

// ---------------- weight transpose f32 -> bf16 : dst[N][ldd] slice = src[K][N]^T ----------------
__global__ void k_transpose_w(const float* __restrict__ src, __bf16* __restrict__ dst,
                              int K, int N, int ldd, int koff) {
  __shared__ float tile[32][33];
  const int bx = blockIdx.x * 32;  // N dim
  const int by = blockIdx.y * 32;  // K dim
  const int tx = threadIdx.x, ty = threadIdx.y;
#pragma unroll
  for (int ii = 0; ii < 4; ++ii) {
    int i = ty + ii * 8;
    tile[i][tx] = src[(size_t)(by + i) * N + bx + tx];
  }
  __syncthreads();
#pragma unroll
  for (int ii = 0; ii < 4; ++ii) {
    int i = ty + ii * 8;
    dst[(size_t)(bx + i) * ldd + koff + by + tx] = (__bf16)tile[tx][i];
  }
}

// ---------------- pack qkv bias ----------------
__global__ void k_pack_bias(const float* __restrict__ bq, const float* __restrict__ bk,
                            const float* __restrict__ bv, float* __restrict__ dst) {
  int i = blockIdx.x * 256 + threadIdx.x;
  if (i < 768) dst[i] = bq[i];
  else if (i < 1536) dst[i] = bk[i - 768];
  else if (i < 2304) dst[i] = bv[i - 1536];
}

// ---------------- LayerNorm f32 -> bf16 (one wave per 768-row) ----------------
__global__ __launch_bounds__(256) void k_layernorm(const float* __restrict__ x,
                                                   const float* __restrict__ g,
                                                   const float* __restrict__ b,
                                                   __bf16* __restrict__ out) {
  const int row = blockIdx.x * 4 + (threadIdx.x >> 6);
  const int lane = threadIdx.x & 63;
  const float* xr = x + (size_t)row * 768;
  float4 v[3];
#pragma unroll
  for (int j = 0; j < 3; ++j) v[j] = *(const float4*)(xr + j * 256 + lane * 4);
  float s = 0.f, ss = 0.f;
#pragma unroll
  for (int j = 0; j < 3; ++j) {
    s += v[j].x + v[j].y + v[j].z + v[j].w;
    ss += v[j].x * v[j].x + v[j].y * v[j].y + v[j].z * v[j].z + v[j].w * v[j].w;
  }
#pragma unroll
  for (int off = 32; off > 0; off >>= 1) {
    s += __shfl_xor(s, off);
    ss += __shfl_xor(ss, off);
  }
  const float mu = s * (1.f / 768.f);
  const float rstd = rsqrtf(ss * (1.f / 768.f) - mu * mu + 1e-5f);
  __bf16* orow = out + (size_t)row * 768;
#pragma unroll
  for (int j = 0; j < 3; ++j) {
    float4 gg = *(const float4*)(g + j * 256 + lane * 4);
    float4 bb = *(const float4*)(b + j * 256 + lane * 4);
    const int base = j * 256 + lane * 4;
    orow[base + 0] = (__bf16)((v[j].x - mu) * rstd * gg.x + bb.x);
    orow[base + 1] = (__bf16)((v[j].y - mu) * rstd * gg.y + bb.y);
    orow[base + 2] = (__bf16)((v[j].z - mu) * rstd * gg.z + bb.z);
    orow[base + 3] = (__bf16)((v[j].w - mu) * rstd * gg.w + bb.w);
  }
}

// ---------------- GEMM: C[M][N] = A[M][K] * BT[N][K]^T + bias (+epilogue) ----------------
// MODE 0: store bf16            (QKV)
// MODE 1: + resid, store f32    (proj, mlp2)
// MODE 2: exact GELU, store bf16 (mlp1)
template <int MODE>
__global__ __launch_bounds__(256) void k_gemm(const __bf16* __restrict__ A,
                                              const __bf16* __restrict__ BT,
                                              const float* __restrict__ bias,
                                              const float* __restrict__ resid,
                                              void* __restrict__ Cout,
                                              int M, int N, int K) {
  __shared__ __bf16 As[128 * 32];
  __shared__ __bf16 Bs[128 * 32];
  const int m0 = blockIdx.y * 128, n0 = blockIdx.x * 128;
  const int tid = threadIdx.x;
  const int wid = tid >> 6, lane = tid & 63;
  const int wm = wid >> 1, wn = wid & 1;
  const int lr = lane & 15, lg = lane >> 4;

  f32x4 acc[4][4] = {};

  for (int k0 = 0; k0 < K; k0 += 32) {
#pragma unroll
    for (int it = 0; it < 2; ++it) {
      int t = tid + it * 256;
      int r = t >> 2, c = (t & 3) * 8;
      gload_lds16(A + (size_t)(m0 + r) * K + k0 + c, As + t * 8);
      gload_lds16(BT + (size_t)(n0 + r) * K + k0 + c, Bs + t * 8);
    }
    __syncthreads();
    bf16x8 af[4], bf[4];
#pragma unroll
    for (int i = 0; i < 4; ++i) af[i] = *(const bf16x8*)(As + (wm * 64 + i * 16 + lr) * 32 + lg * 8);
#pragma unroll
    for (int j = 0; j < 4; ++j) bf[j] = *(const bf16x8*)(Bs + (wn * 64 + j * 16 + lr) * 32 + lg * 8);
#pragma unroll
    for (int i = 0; i < 4; ++i)
#pragma unroll
      for (int j = 0; j < 4; ++j)
        acc[i][j] = __builtin_amdgcn_mfma_f32_16x16x32_bf16(af[i], bf[j], acc[i][j], 0, 0, 0);
    __syncthreads();
  }

#pragma unroll
  for (int i = 0; i < 4; ++i)
#pragma unroll
    for (int j = 0; j < 4; ++j)
#pragma unroll
      for (int r = 0; r < 4; ++r) {
        int row = m0 + wm * 64 + i * 16 + lg * 4 + r;
        int col = n0 + wn * 64 + j * 16 + lr;
        float v = acc[i][j][r] + bias[col];
        size_t idx = (size_t)row * N + col;
        if constexpr (MODE == 0) {
          ((__bf16*)Cout)[idx] = (__bf16)v;
        } else if constexpr (MODE == 1) {
          ((float*)Cout)[idx] = v + resid[idx];
        } else {
          float gv = 0.5f * v * (1.f + erff(v * 0.70710678118654752f));
          ((__bf16*)Cout)[idx] = (__bf16)gv;
        }
      }
}

// ---------------- V transpose: vt[b][d][s] = v[b][s][d] (v = qkv cols 1536..2303) ----------------
__global__ void k_transpose_v(const __bf16* __restrict__ qkv, __bf16* __restrict__ vt) {
  __shared__ __bf16 tile[32][33];
  const int s0 = blockIdx.x * 32, d0 = blockIdx.y * 32, b = blockIdx.z;
  const int tx = threadIdx.x, ty = threadIdx.y;
#pragma unroll
  for (int ii = 0; ii < 4; ++ii) {
    int i = ty + ii * 8;
    tile[i][tx] = qkv[(size_t)(b * 4096 + s0 + i) * 2304 + 1536 + d0 + tx];
  }
  __syncthreads();
#pragma unroll
  for (int ii = 0; ii < 4; ++ii) {
    int i = ty + ii * 8;
    vt[(size_t)(b * 768 + d0 + i) * 4096 + s0 + tx] = tile[tx][i];
  }
}

// ---------------- fused attention with head-axis softmax (v2) ----------------
// grid (64 qtiles, 2 ksplit, 2 batch) x 1024 threads.
// 16 waves = (qs in 0..3) x (head-pair hp in 0..3); each wave: 16 q-rows, 2 heads,
// k-range of 2048. K/VT loads are qs-invariant -> L1/L2 broadcast across qs waves.
// Head-softmax denominator: bf16 partials in LDS, exchanged across hp waves.
// Output halves (ksplit) stored side by side [8192][1536]; proj GEMM sums them.
__global__ __launch_bounds__(1024) void k_attn(const __bf16* __restrict__ qkv,
                                               const __bf16* __restrict__ vt,
                                               __bf16* __restrict__ attn_out) {
  extern __shared__ __bf16 psum[];  // [4 qs][4 hp][2 kt][16 row][20 pad]
  const int b = blockIdx.z;
  const int ks = blockIdx.y;
  const int wid = threadIdx.x >> 6;
  const int qs = wid & 3, hp = wid >> 2;
  const int q0 = blockIdx.x * 64 + qs * 16;
  const int lane = threadIdx.x & 63;
  const int lr = lane & 15, lg = lane >> 4;
  const int h0 = hp * 2;

  const __bf16* Qb = qkv + (size_t)(b * 4096 + q0) * 2304;
  const __bf16* Kb = qkv + (size_t)b * 4096 * 2304 + 768;
  const __bf16* VTb = vt + (size_t)b * 768 * 4096;

  // hoist Q fragments (B-operand of energy mfma): lane holds Q row q0+lr, 8 d's
  bf16x8 qf[2][3];
#pragma unroll
  for (int hh = 0; hh < 2; ++hh)
#pragma unroll
    for (int dc = 0; dc < 3; ++dc)
      qf[hh][dc] = *(const bf16x8*)(Qb + (size_t)lr * 2304 + (h0 + hh) * 96 + dc * 32 + lg * 8);

  f32x4 o[2][6] = {};
  // permuted K-row for the A-frag: row i holds global k-row k0 + sig(i) (+4 for kt=1)
  const int sig = ((lr >> 2) * 8) + (lr & 3);
  const int kbeg = ks * 2048, kend = kbeg + 2048;

  // LDS index helpers (bf16, inner pad 20 -> 2-way bank aliasing only)
  const int my_row_base = ((qs * 4 + hp) * 2) * 16 * 20;  // + kt*320 + row*20 + lr

  for (int k0 = kbeg; k0 < kend; k0 += 32) {
    f32x4 e[2][2] = {};
#pragma unroll
    for (int kt = 0; kt < 2; ++kt) {
      const __bf16* Krow = Kb + (size_t)(k0 + sig + kt * 4) * 2304;
#pragma unroll
      for (int hh = 0; hh < 2; ++hh)
#pragma unroll
        for (int dc = 0; dc < 3; ++dc) {
          bf16x8 kf = *(const bf16x8*)(Krow + (h0 + hh) * 96 + dc * 32 + lg * 8);
          e[hh][kt] = __builtin_amdgcn_mfma_f32_16x16x32_bf16(kf, qf[hh][dc], e[hh][kt], 0, 0, 0);
        }
    }
    // exp + per-wave (2-head) partial sums -> LDS (bf16)
    float ps[2][4];
#pragma unroll
    for (int kt = 0; kt < 2; ++kt)
#pragma unroll
      for (int r = 0; r < 4; ++r) {
        float e0 = __expf(e[0][kt][r]);
        float e1 = __expf(e[1][kt][r]);
        e[0][kt][r] = e0;
        e[1][kt][r] = e1;
        float p = e0 + e1;
        ps[kt][r] = p;
        psum[my_row_base + kt * 320 + (lg * 4 + r) * 20 + lr] = (__bf16)p;
      }
    __syncthreads();
    float inv[2][4];
#pragma unroll
    for (int kt = 0; kt < 2; ++kt)
#pragma unroll
      for (int r = 0; r < 4; ++r) {
        float tot = ps[kt][r];
#pragma unroll
        for (int w = 1; w < 4; ++w) {
          int op = (hp + w) & 3;
          tot += (float)psum[((qs * 4 + op) * 2 + kt) * 320 + (lg * 4 + r) * 20 + lr];
        }
        inv[kt][r] = 0.03608439182435161f / tot;  // (1/sqrt(768)) / sum_h exp
      }
    __syncthreads();
    // P fragments: direct A-frag of PV mfma (k = lg*8 + (kt*4+r))
    bf16x8 pf[2];
#pragma unroll
    for (int hh = 0; hh < 2; ++hh)
#pragma unroll
      for (int e2 = 0; e2 < 8; ++e2) {
        const int kt = e2 >> 2, r = e2 & 3;
        pf[hh][e2] = (__bf16)(e[hh][kt][r] * inv[kt][r]);
      }
    // PV: O[q][d] += P * V, V via VT rows (contiguous 16B per lane)
#pragma unroll
    for (int hh = 0; hh < 2; ++hh)
#pragma unroll
      for (int db = 0; db < 6; ++db) {
        bf16x8 vf = *(const bf16x8*)(VTb + (size_t)((h0 + hh) * 96 + db * 16 + lr) * 4096 + k0 + lg * 8);
        o[hh][db] = __builtin_amdgcn_mfma_f32_16x16x32_bf16(pf[hh], vf, o[hh][db], 0, 0, 0);
      }
  }

#pragma unroll
  for (int hh = 0; hh < 2; ++hh)
#pragma unroll
    for (int db = 0; db < 6; ++db)
#pragma unroll
      for (int r = 0; r < 4; ++r)
        attn_out[(size_t)(b * 4096 + q0 + lg * 4 + r) * 1536 + ks * 768 + (h0 + hh) * 96 + db * 16 + lr] =
            (__bf16)o[hh][db][r];
}

// ---------------- launcher ----------------
extern "C" void kernel_launch(void* const* d_in, const int* in_sizes, int n_in,
                              void* d_out, int out_size, void* d_ws, size_t ws_size,
                              hipStream_t stream) {
  (void)in_sizes; (void)n_in; (void)out_size; (void)ws_size;
  const float* x     = (const float*)d_in[0];
  const float* ln1_g = (const float*)d_in[1];
  const float* ln1_b = (const float*)d_in[2];
  const float* wq    = (const float*)d_in[3];
  const float* bq    = (const float*)d_in[4];
  const float* wk    = (const float*)d_in[5];
  const float* bk    = (const float*)d_in[6];
  const float* wv    = (const float*)d_in[7];
  const float* bv    = (const float*)d_in[8];
  const float* wp    = (const float*)d_in[9];
  const float* bp    = (const float*)d_in[10];
  const float* ln2_g = (const float*)d_in[11];
  const float* ln2_b = (const float*)d_in[12];
  const float* w1    = (const float*)d_in[13];
  const float* b1    = (const float*)d_in[14];
  const float* w2    = (const float*)d_in[15];
  const float* b2    = (const float*)d_in[16];

  char* ws = (char*)d_ws;
  const size_t o_wqkvT = 0;                                   // [2304][768] bf16
  const size_t o_wpT   = o_wqkvT + (size_t)2304 * 768 * 2;    // [768][1536] bf16 (doubled)
  const size_t o_w1T   = o_wpT   + (size_t)768 * 1536 * 2;    // [3072][768] bf16
  const size_t o_w2T   = o_w1T   + (size_t)768 * 3072 * 2;    // [768][3072] bf16
  const size_t o_bqkv  = o_w2T   + (size_t)3072 * 768 * 2;    // [2304] f32
  const size_t o_xn    = o_bqkv  + (size_t)2304 * 4;          // [8192][768] bf16
  const size_t o_qkv   = o_xn    + (size_t)8192 * 768 * 2;    // [8192][2304] bf16
  const size_t o_vt    = o_qkv   + (size_t)8192 * 2304 * 2;   // [2][768][4096] bf16
  const size_t o_attn  = o_vt    + (size_t)2 * 768 * 4096 * 2;// [8192][1536] bf16 (2 k-halves)
  const size_t o_x1    = o_attn  + (size_t)8192 * 1536 * 2;   // [8192][768] f32
  const size_t o_hmid  = o_xn;   // reuse xn+qkv region: [8192][3072] bf16 (fits exactly)
  const size_t o_xn2   = o_vt;   // reuse vt region: [8192][768] bf16

  __bf16* wqkvT = (__bf16*)(ws + o_wqkvT);
  __bf16* wpT   = (__bf16*)(ws + o_wpT);
  __bf16* w1T   = (__bf16*)(ws + o_w1T);
  __bf16* w2T   = (__bf16*)(ws + o_w2T);
  float*  bqkv  = (float*)(ws + o_bqkv);
  __bf16* xn    = (__bf16*)(ws + o_xn);
  __bf16* qkvb  = (__bf16*)(ws + o_qkv);
  __bf16* vtb   = (__bf16*)(ws + o_vt);
  __bf16* attnb = (__bf16*)(ws + o_attn);
  float*  x1    = (float*)(ws + o_x1);
  __bf16* hmid  = (__bf16*)(ws + o_hmid);
  __bf16* xn2   = (__bf16*)(ws + o_xn2);

  dim3 tb(32, 8);
  k_transpose_w<<<dim3(24, 24), tb, 0, stream>>>(wq, wqkvT, 768, 768, 768, 0);
  k_transpose_w<<<dim3(24, 24), tb, 0, stream>>>(wk, wqkvT + (size_t)768 * 768, 768, 768, 768, 0);
  k_transpose_w<<<dim3(24, 24), tb, 0, stream>>>(wv, wqkvT + (size_t)2 * 768 * 768, 768, 768, 768, 0);
  // wp transposed TWICE into [768][1536]: (O1|O2) @ (wp;wp) sums the k-split halves
  k_transpose_w<<<dim3(24, 24), tb, 0, stream>>>(wp, wpT, 768, 768, 1536, 0);
  k_transpose_w<<<dim3(24, 24), tb, 0, stream>>>(wp, wpT, 768, 768, 1536, 768);
  k_transpose_w<<<dim3(96, 24), tb, 0, stream>>>(w1, w1T, 768, 3072, 768, 0);
  k_transpose_w<<<dim3(24, 96), tb, 0, stream>>>(w2, w2T, 3072, 768, 3072, 0);
  k_pack_bias<<<9, 256, 0, stream>>>(bq, bk, bv, bqkv);

  // LN1 -> xn
  k_layernorm<<<2048, 256, 0, stream>>>(x, ln1_g, ln1_b, xn);
  // QKV projection (fused q|k|v)
  k_gemm<0><<<dim3(18, 64), 256, 0, stream>>>(xn, wqkvT, bqkv, nullptr, qkvb, 8192, 2304, 768);
  // V transpose
  k_transpose_v<<<dim3(128, 24, 2), tb, 0, stream>>>(qkvb, vtb);
  // attention: 256 blocks x 16 waves, 40KB dynamic LDS
  k_attn<<<dim3(64, 2, 2), 1024, 4 * 4 * 2 * 16 * 20 * 2, stream>>>(qkvb, vtb, attnb);
  // output projection over K=1536 (sums the two k-split halves) + residual -> x1 (f32)
  k_gemm<1><<<dim3(6, 64), 256, 0, stream>>>(attnb, wpT, bp, x, x1, 8192, 768, 1536);
  // LN2 -> xn2
  k_layernorm<<<2048, 256, 0, stream>>>(x1, ln2_g, ln2_b, xn2);
  // MLP1 + exact GELU -> hmid
  k_gemm<2><<<dim3(24, 64), 256, 0, stream>>>(xn2, w1T, b1, nullptr, hmid, 8192, 3072, 768);
  // MLP2 + residual -> out (f32)
  k_gemm<1><<<dim3(6, 64), 256, 0, stream>>>(hmid, w2T, b2, x1, (float*)d_out, 8192, 768, 3072);
}

// Round 3
// 767.104 us; speedup vs baseline: 1.3654x; 1.3654x over previous
//
#include <hip/hip_runtime.h>
#include <cstdint>
#include <cstddef>

#define AS1 __attribute__((address_space(1)))
#define AS3 __attribute__((address_space(3)))

typedef __attribute__((ext_vector_type(8))) __bf16 bf16x8;
typedef __attribute__((ext_vector_type(4))) float f32x4;

__device__ __forceinline__ void gload_lds16(const void* g, void* l) {
  __builtin_amdgcn_global_load_lds((AS1 void*)g, (AS3 void*)l, 16, 0, 0);
}

// ---------------- weight transpose f32 -> bf16 : dst[N][ldd] slice = src[K][N]^T ----------------
__global__ void k_transpose_w(const float* __restrict__ src, __bf16* __restrict__ dst,
                              int K, int N, int ldd, int koff) {
  __shared__ float tile[32][33];
  const int bx = blockIdx.x * 32;  // N dim
  const int by = blockIdx.y * 32;  // K dim
  const int tx = threadIdx.x, ty = threadIdx.y;
#pragma unroll
  for (int ii = 0; ii < 4; ++ii) {
    int i = ty + ii * 8;
    tile[i][tx] = src[(size_t)(by + i) * N + bx + tx];
  }
  __syncthreads();
#pragma unroll
  for (int ii = 0; ii < 4; ++ii) {
    int i = ty + ii * 8;
    dst[(size_t)(bx + i) * ldd + koff + by + tx] = (__bf16)tile[tx][i];
  }
}

// ---------------- pack qkv bias ----------------
__global__ void k_pack_bias(const float* __restrict__ bq, const float* __restrict__ bk,
                            const float* __restrict__ bv, float* __restrict__ dst) {
  int i = blockIdx.x * 256 + threadIdx.x;
  if (i < 768) dst[i] = bq[i];
  else if (i < 1536) dst[i] = bk[i - 768];
  else if (i < 2304) dst[i] = bv[i - 1536];
}

// ---------------- LayerNorm f32 -> bf16 (one wave per 768-row) ----------------
__global__ __launch_bounds__(256) void k_layernorm(const float* __restrict__ x,
                                                   const float* __restrict__ g,
                                                   const float* __restrict__ b,
                                                   __bf16* __restrict__ out) {
  const int row = blockIdx.x * 4 + (threadIdx.x >> 6);
  const int lane = threadIdx.x & 63;
  const float* xr = x + (size_t)row * 768;
  float4 v[3];
#pragma unroll
  for (int j = 0; j < 3; ++j) v[j] = *(const float4*)(xr + j * 256 + lane * 4);
  float s = 0.f, ss = 0.f;
#pragma unroll
  for (int j = 0; j < 3; ++j) {
    s += v[j].x + v[j].y + v[j].z + v[j].w;
    ss += v[j].x * v[j].x + v[j].y * v[j].y + v[j].z * v[j].z + v[j].w * v[j].w;
  }
#pragma unroll
  for (int off = 32; off > 0; off >>= 1) {
    s += __shfl_xor(s, off);
    ss += __shfl_xor(ss, off);
  }
  const float mu = s * (1.f / 768.f);
  const float rstd = rsqrtf(ss * (1.f / 768.f) - mu * mu + 1e-5f);
  __bf16* orow = out + (size_t)row * 768;
#pragma unroll
  for (int j = 0; j < 3; ++j) {
    float4 gg = *(const float4*)(g + j * 256 + lane * 4);
    float4 bb = *(const float4*)(b + j * 256 + lane * 4);
    const int base = j * 256 + lane * 4;
    orow[base + 0] = (__bf16)((v[j].x - mu) * rstd * gg.x + bb.x);
    orow[base + 1] = (__bf16)((v[j].y - mu) * rstd * gg.y + bb.y);
    orow[base + 2] = (__bf16)((v[j].z - mu) * rstd * gg.z + bb.z);
    orow[base + 3] = (__bf16)((v[j].w - mu) * rstd * gg.w + bb.w);
  }
}

// ---------------- GEMM: C[M][N] = A[M][K] * BT[N][K]^T + bias (+epilogue) ----------------
template <int MODE>
__global__ __launch_bounds__(256) void k_gemm(const __bf16* __restrict__ A,
                                              const __bf16* __restrict__ BT,
                                              const float* __restrict__ bias,
                                              const float* __restrict__ resid,
                                              void* __restrict__ Cout,
                                              int M, int N, int K) {
  __shared__ __bf16 As[128 * 32];
  __shared__ __bf16 Bs[128 * 32];
  const int m0 = blockIdx.y * 128, n0 = blockIdx.x * 128;
  const int tid = threadIdx.x;
  const int wid = tid >> 6, lane = tid & 63;
  const int wm = wid >> 1, wn = wid & 1;
  const int lr = lane & 15, lg = lane >> 4;

  f32x4 acc[4][4] = {};

  for (int k0 = 0; k0 < K; k0 += 32) {
#pragma unroll
    for (int it = 0; it < 2; ++it) {
      int t = tid + it * 256;
      int r = t >> 2, c = (t & 3) * 8;
      gload_lds16(A + (size_t)(m0 + r) * K + k0 + c, As + t * 8);
      gload_lds16(BT + (size_t)(n0 + r) * K + k0 + c, Bs + t * 8);
    }
    __syncthreads();
    bf16x8 af[4], bf[4];
#pragma unroll
    for (int i = 0; i < 4; ++i) af[i] = *(const bf16x8*)(As + (wm * 64 + i * 16 + lr) * 32 + lg * 8);
#pragma unroll
    for (int j = 0; j < 4; ++j) bf[j] = *(const bf16x8*)(Bs + (wn * 64 + j * 16 + lr) * 32 + lg * 8);
#pragma unroll
    for (int i = 0; i < 4; ++i)
#pragma unroll
      for (int j = 0; j < 4; ++j)
        acc[i][j] = __builtin_amdgcn_mfma_f32_16x16x32_bf16(af[i], bf[j], acc[i][j], 0, 0, 0);
    __syncthreads();
  }

#pragma unroll
  for (int i = 0; i < 4; ++i)
#pragma unroll
    for (int j = 0; j < 4; ++j)
#pragma unroll
      for (int r = 0; r < 4; ++r) {
        int row = m0 + wm * 64 + i * 16 + lg * 4 + r;
        int col = n0 + wn * 64 + j * 16 + lr;
        float v = acc[i][j][r] + bias[col];
        size_t idx = (size_t)row * N + col;
        if constexpr (MODE == 0) {
          ((__bf16*)Cout)[idx] = (__bf16)v;
        } else if constexpr (MODE == 1) {
          ((float*)Cout)[idx] = v + resid[idx];
        } else {
          float gv = 0.5f * v * (1.f + erff(v * 0.70710678118654752f));
          ((__bf16*)Cout)[idx] = (__bf16)gv;
        }
      }
}

// ---------------- pack K into fragment-major KA ----------------
// KA[b][kb][hp][kt][hh][dc][lane][8] = K[b][kb*32 + sig(lane&15) + 4*kt][hp*192+hh*96+dc*32+(lane>>4)*8 + e]
// sig(i) = (i>>2)*8 + (i&3). Reads are 16-row gathers (paid once); writes fully coalesced.
__global__ __launch_bounds__(256) void k_pack_ka(const __bf16* __restrict__ qkv,
                                                 __bf16* __restrict__ KA) {
  const int kb = blockIdx.x, b = blockIdx.y;
  const int t = threadIdx.x;
#pragma unroll
  for (int i = 0; i < 12; ++i) {
    int c = t + i * 256;  // 0..3071
    int lane = c & 63, f = c >> 6;
    int dc = f % 3, hh = (f / 3) & 1, kt = (f / 6) & 1, hp = f / 12;
    int lr = lane & 15;
    int row = kb * 32 + (lr >> 2) * 8 + (lr & 3) + kt * 4;
    int col = 768 + hp * 192 + hh * 96 + dc * 32 + (lane >> 4) * 8;
    bf16x8 v = *(const bf16x8*)(qkv + (size_t)(b * 4096 + row) * 2304 + col);
    *(bf16x8*)(KA + ((size_t)(b * 128 + kb) * 3072 + c) * 8) = v;
  }
}

// ---------------- pack V (transposed) into fragment-major VA ----------------
// VA[b][kb][hp][hh][db][lane][8] = V[b][kb*32 + (lane>>4)*8 + e][hp*192+hh*96+db*16+(lane&15)]
__global__ __launch_bounds__(256) void k_pack_va(const __bf16* __restrict__ qkv,
                                                 __bf16* __restrict__ VA) {
  __shared__ __bf16 vtile[32][772];
  const int kb = blockIdx.x, b = blockIdx.y;
  const int t = threadIdx.x;
#pragma unroll
  for (int i = 0; i < 12; ++i) {
    int c = t + i * 256;
    int row = c / 96, c8 = c % 96;
    *(bf16x8*)(&vtile[row][c8 * 8]) =
        *(const bf16x8*)(qkv + (size_t)(b * 4096 + kb * 32 + row) * 2304 + 1536 + c8 * 8);
  }
  __syncthreads();
#pragma unroll
  for (int i = 0; i < 12; ++i) {
    int c = t + i * 256;
    int lane = c & 63, f = c >> 6;
    int db = f % 6, hh = (f / 6) & 1, hp = f / 12;
    int d = hp * 192 + hh * 96 + db * 16 + (lane & 15);
    int krow = (lane >> 4) * 8;
    bf16x8 v;
#pragma unroll
    for (int e = 0; e < 8; ++e) v[e] = vtile[krow + e][d];
    *(bf16x8*)(VA + ((size_t)(b * 128 + kb) * 3072 + c) * 8) = v;
  }
}

// ---------------- fused attention v3: fragment-major coalesced loads ----------------
// grid: 512 linear blocks; slice = bid&7 -> (b=slice>>2, ks=slice&3) pinned per-XCD
// (dispatch round-robins bid%8), qb = bid>>3. Block: 16 waves = (qs 0..3) x (hp 0..3),
// 64 q-rows, k-range 1024 (32 kb of 32). All hot-loop global loads: 16B/lane coalesced.
__global__ __launch_bounds__(1024) void k_attn(const __bf16* __restrict__ qkv,
                                               const __bf16* __restrict__ KA,
                                               const __bf16* __restrict__ VA,
                                               __bf16* __restrict__ attn4) {
  __shared__ __bf16 psum[10240];  // [qs4][hp4][kt2][row16][20]
  const int bid = blockIdx.x;
  const int slice = bid & 7;
  const int b = slice >> 2, ks = slice & 3;
  const int qb = bid >> 3;
  const int wid = threadIdx.x >> 6;
  const int qs = wid & 3, hp = wid >> 2;
  const int q0 = qb * 64 + qs * 16;
  const int lane = threadIdx.x & 63;
  const int lr = lane & 15, lg = lane >> 4;

  // Q fragments (B-operand): lane holds Q row q0+lr, 8 d's (one-time 16-row gather)
  const __bf16* Qb = qkv + (size_t)(b * 4096 + q0) * 2304;
  bf16x8 qf[2][3];
#pragma unroll
  for (int hh = 0; hh < 2; ++hh)
#pragma unroll
    for (int dc = 0; dc < 3; ++dc)
      qf[hh][dc] = *(const bf16x8*)(Qb + (size_t)lr * 2304 + (hp * 2 + hh) * 96 + dc * 32 + lg * 8);

  const int kb0 = ks * 32;
  const __bf16* pK = KA + ((size_t)(b * 128 + kb0) * 4 + hp) * 6144 + lane * 8;
  const __bf16* pV = VA + ((size_t)(b * 128 + kb0) * 4 + hp) * 6144 + lane * 8;

  f32x4 o[2][6] = {};
  const int pw = ((qs * 4 + hp) * 2) * 320;  // psum write base

  for (int kb = 0; kb < 32; ++kb) {
    f32x4 e[2][2] = {};
#pragma unroll
    for (int kt = 0; kt < 2; ++kt)
#pragma unroll
      for (int hh = 0; hh < 2; ++hh)
#pragma unroll
        for (int dc = 0; dc < 3; ++dc) {
          bf16x8 kf = *(const bf16x8*)(pK + (kt * 6 + hh * 3 + dc) * 512);
          e[hh][kt] = __builtin_amdgcn_mfma_f32_16x16x32_bf16(kf, qf[hh][dc], e[hh][kt], 0, 0, 0);
        }
#pragma unroll
    for (int kt = 0; kt < 2; ++kt)
#pragma unroll
      for (int r = 0; r < 4; ++r) {
        float e0 = __expf(e[0][kt][r]);
        float e1 = __expf(e[1][kt][r]);
        e[0][kt][r] = e0;
        e[1][kt][r] = e1;
        psum[pw + kt * 320 + (lg * 4 + r) * 20 + lr] = (__bf16)(e0 + e1);
      }
    __syncthreads();
    float inv[2][4];
#pragma unroll
    for (int kt = 0; kt < 2; ++kt)
#pragma unroll
      for (int r = 0; r < 4; ++r) {
        float tot = 0.f;
#pragma unroll
        for (int w = 0; w < 4; ++w)
          tot += (float)psum[((qs * 4 + w) * 2 + kt) * 320 + (lg * 4 + r) * 20 + lr];
        inv[kt][r] = 0.03608439182435161f / tot;  // (1/sqrt(768)) / sum_h exp
      }
    __syncthreads();
    bf16x8 pf[2];
#pragma unroll
    for (int hh = 0; hh < 2; ++hh)
#pragma unroll
      for (int e2 = 0; e2 < 8; ++e2) {
        const int kt = e2 >> 2, r = e2 & 3;
        pf[hh][e2] = (__bf16)(e[hh][kt][r] * inv[kt][r]);
      }
#pragma unroll
    for (int hh = 0; hh < 2; ++hh)
#pragma unroll
      for (int db = 0; db < 6; ++db) {
        bf16x8 vf = *(const bf16x8*)(pV + (hh * 6 + db) * 512);
        o[hh][db] = __builtin_amdgcn_mfma_f32_16x16x32_bf16(pf[hh], vf, o[hh][db], 0, 0, 0);
      }
    pK += 24576;
    pV += 24576;
  }

#pragma unroll
  for (int hh = 0; hh < 2; ++hh)
#pragma unroll
    for (int db = 0; db < 6; ++db)
#pragma unroll
      for (int r = 0; r < 4; ++r)
        attn4[(size_t)(b * 4096 + q0 + lg * 4 + r) * 3072 + ks * 768 +
              (hp * 2 + hh) * 96 + db * 16 + lr] = (__bf16)o[hh][db][r];
}

// ---------------- reduce 4 k-split slices -> bf16 ----------------
__global__ __launch_bounds__(256) void k_reduce_attn(const __bf16* __restrict__ attn4,
                                                     __bf16* __restrict__ out) {
  int g = blockIdx.x * 256 + threadIdx.x;  // chunk of 8, total 8192*96
  int row = g / 96, c8 = g % 96;
  const __bf16* p = attn4 + (size_t)row * 3072 + c8 * 8;
  float acc[8] = {};
#pragma unroll
  for (int s = 0; s < 4; ++s) {
    bf16x8 v = *(const bf16x8*)(p + s * 768);
#pragma unroll
    for (int e = 0; e < 8; ++e) acc[e] += (float)v[e];
  }
  bf16x8 r;
#pragma unroll
  for (int e = 0; e < 8; ++e) r[e] = (__bf16)acc[e];
  *(bf16x8*)(out + (size_t)row * 768 + c8 * 8) = r;
}

// ---------------- launcher ----------------
extern "C" void kernel_launch(void* const* d_in, const int* in_sizes, int n_in,
                              void* d_out, int out_size, void* d_ws, size_t ws_size,
                              hipStream_t stream) {
  (void)in_sizes; (void)n_in; (void)out_size; (void)ws_size;
  const float* x     = (const float*)d_in[0];
  const float* ln1_g = (const float*)d_in[1];
  const float* ln1_b = (const float*)d_in[2];
  const float* wq    = (const float*)d_in[3];
  const float* bq    = (const float*)d_in[4];
  const float* wk    = (const float*)d_in[5];
  const float* bk    = (const float*)d_in[6];
  const float* wv    = (const float*)d_in[7];
  const float* bv    = (const float*)d_in[8];
  const float* wp    = (const float*)d_in[9];
  const float* bp    = (const float*)d_in[10];
  const float* ln2_g = (const float*)d_in[11];
  const float* ln2_b = (const float*)d_in[12];
  const float* w1    = (const float*)d_in[13];
  const float* b1    = (const float*)d_in[14];
  const float* w2    = (const float*)d_in[15];
  const float* b2    = (const float*)d_in[16];

  char* ws = (char*)d_ws;
  const size_t o_wqkvT = 0;                                   // [2304][768] bf16
  const size_t o_wpT   = o_wqkvT + (size_t)2304 * 768 * 2;    // [768][768] bf16
  const size_t o_w1T   = o_wpT   + (size_t)768 * 768 * 2;     // [3072][768] bf16
  const size_t o_w2T   = o_w1T   + (size_t)768 * 3072 * 2;    // [768][3072] bf16
  const size_t o_bqkv  = o_w2T   + (size_t)3072 * 768 * 2;    // [2304] f32
  const size_t o_xn    = o_bqkv  + (size_t)2304 * 4;          // [8192][768] bf16
  const size_t o_qkv   = o_xn    + (size_t)8192 * 768 * 2;    // [8192][2304] bf16
  const size_t o_KA    = o_qkv   + (size_t)8192 * 2304 * 2;   // [2][128][3072][8] bf16
  const size_t o_VA    = o_KA    + (size_t)2 * 128 * 3072 * 8 * 2;
  const size_t o_attn4 = o_VA    + (size_t)2 * 128 * 3072 * 8 * 2;  // [8192][3072] bf16
  // aliases (lifetime-disjoint):
  const size_t o_x1      = o_attn4;  // [8192][768] f32 (written after attn4 last read)
  const size_t o_attnred = o_KA;     // [8192][768] bf16 (KA dead after attention)
  const size_t o_xn2     = o_VA;     // [8192][768] bf16 (VA dead after attention)
  const size_t o_hmid    = o_xn;     // [8192][3072] bf16 (spans xn+qkv, both dead)

  __bf16* wqkvT = (__bf16*)(ws + o_wqkvT);
  __bf16* wpT   = (__bf16*)(ws + o_wpT);
  __bf16* w1T   = (__bf16*)(ws + o_w1T);
  __bf16* w2T   = (__bf16*)(ws + o_w2T);
  float*  bqkv  = (float*)(ws + o_bqkv);
  __bf16* xn    = (__bf16*)(ws + o_xn);
  __bf16* qkvb  = (__bf16*)(ws + o_qkv);
  __bf16* KA    = (__bf16*)(ws + o_KA);
  __bf16* VA    = (__bf16*)(ws + o_VA);
  __bf16* attn4 = (__bf16*)(ws + o_attn4);
  float*  x1    = (float*)(ws + o_x1);
  __bf16* attnr = (__bf16*)(ws + o_attnred);
  __bf16* xn2   = (__bf16*)(ws + o_xn2);
  __bf16* hmid  = (__bf16*)(ws + o_hmid);

  dim3 tb(32, 8);
  k_transpose_w<<<dim3(24, 24), tb, 0, stream>>>(wq, wqkvT, 768, 768, 768, 0);
  k_transpose_w<<<dim3(24, 24), tb, 0, stream>>>(wk, wqkvT + (size_t)768 * 768, 768, 768, 768, 0);
  k_transpose_w<<<dim3(24, 24), tb, 0, stream>>>(wv, wqkvT + (size_t)2 * 768 * 768, 768, 768, 768, 0);
  k_transpose_w<<<dim3(24, 24), tb, 0, stream>>>(wp, wpT, 768, 768, 768, 0);
  k_transpose_w<<<dim3(96, 24), tb, 0, stream>>>(w1, w1T, 768, 3072, 768, 0);
  k_transpose_w<<<dim3(24, 96), tb, 0, stream>>>(w2, w2T, 3072, 768, 3072, 0);
  k_pack_bias<<<9, 256, 0, stream>>>(bq, bk, bv, bqkv);

  // LN1 -> xn
  k_layernorm<<<2048, 256, 0, stream>>>(x, ln1_g, ln1_b, xn);
  // QKV projection (fused q|k|v)
  k_gemm<0><<<dim3(18, 64), 256, 0, stream>>>(xn, wqkvT, bqkv, nullptr, qkvb, 8192, 2304, 768);
  // pack K and V into fragment-major layouts
  k_pack_ka<<<dim3(128, 2), 256, 0, stream>>>(qkvb, KA);
  k_pack_va<<<dim3(128, 2), 256, 0, stream>>>(qkvb, VA);
  // attention: 512 blocks x 16 waves, slice pinned per XCD via bid&7
  k_attn<<<512, 1024, 0, stream>>>(qkvb, KA, VA, attn4);
  // sum 4 k-split slices
  k_reduce_attn<<<3072, 256, 0, stream>>>(attn4, attnr);
  // output projection + residual -> x1 (f32)
  k_gemm<1><<<dim3(6, 64), 256, 0, stream>>>(attnr, wpT, bp, x, x1, 8192, 768, 768);
  // LN2 -> xn2
  k_layernorm<<<2048, 256, 0, stream>>>(x1, ln2_g, ln2_b, xn2);
  // MLP1 + exact GELU -> hmid
  k_gemm<2><<<dim3(24, 64), 256, 0, stream>>>(xn2, w1T, b1, nullptr, hmid, 8192, 3072, 768);
  // MLP2 + residual -> out (f32)
  k_gemm<1><<<dim3(6, 64), 256, 0, stream>>>(hmid, w2T, b2, x1, (float*)d_out, 8192, 768, 3072);
}

// Round 4
// 754.345 us; speedup vs baseline: 1.3885x; 1.0169x over previous
//
#include <hip/hip_runtime.h>
#include <cstdint>
#include <cstddef>

#define AS1 __attribute__((address_space(1)))
#define AS3 __attribute__((address_space(3)))

typedef __attribute__((ext_vector_type(8))) __bf16 bf16x8;
typedef __attribute__((ext_vector_type(4))) float f32x4;

__device__ __forceinline__ void gload_lds16(const void* g, void* l) {
  __builtin_amdgcn_global_load_lds((AS1 void*)g, (AS3 void*)l, 16, 0, 0);
}

// ---------------- weight transpose f32 -> bf16 : dst[N][ldd] slice = src[K][N]^T ----------------
__global__ void k_transpose_w(const float* __restrict__ src, __bf16* __restrict__ dst,
                              int K, int N, int ldd, int koff) {
  __shared__ float tile[32][33];
  const int bx = blockIdx.x * 32;  // N dim
  const int by = blockIdx.y * 32;  // K dim
  const int tx = threadIdx.x, ty = threadIdx.y;
#pragma unroll
  for (int ii = 0; ii < 4; ++ii) {
    int i = ty + ii * 8;
    tile[i][tx] = src[(size_t)(by + i) * N + bx + tx];
  }
  __syncthreads();
#pragma unroll
  for (int ii = 0; ii < 4; ++ii) {
    int i = ty + ii * 8;
    dst[(size_t)(bx + i) * ldd + koff + by + tx] = (__bf16)tile[tx][i];
  }
}

// ---------------- pack qkv bias ----------------
__global__ void k_pack_bias(const float* __restrict__ bq, const float* __restrict__ bk,
                            const float* __restrict__ bv, float* __restrict__ dst) {
  int i = blockIdx.x * 256 + threadIdx.x;
  if (i < 768) dst[i] = bq[i];
  else if (i < 1536) dst[i] = bk[i - 768];
  else if (i < 2304) dst[i] = bv[i - 1536];
}

// ---------------- LayerNorm f32 -> bf16 (one wave per 768-row) ----------------
__global__ __launch_bounds__(256) void k_layernorm(const float* __restrict__ x,
                                                   const float* __restrict__ g,
                                                   const float* __restrict__ b,
                                                   __bf16* __restrict__ out) {
  const int row = blockIdx.x * 4 + (threadIdx.x >> 6);
  const int lane = threadIdx.x & 63;
  const float* xr = x + (size_t)row * 768;
  float4 v[3];
#pragma unroll
  for (int j = 0; j < 3; ++j) v[j] = *(const float4*)(xr + j * 256 + lane * 4);
  float s = 0.f, ss = 0.f;
#pragma unroll
  for (int j = 0; j < 3; ++j) {
    s += v[j].x + v[j].y + v[j].z + v[j].w;
    ss += v[j].x * v[j].x + v[j].y * v[j].y + v[j].z * v[j].z + v[j].w * v[j].w;
  }
#pragma unroll
  for (int off = 32; off > 0; off >>= 1) {
    s += __shfl_xor(s, off);
    ss += __shfl_xor(ss, off);
  }
  const float mu = s * (1.f / 768.f);
  const float rstd = rsqrtf(ss * (1.f / 768.f) - mu * mu + 1e-5f);
  __bf16* orow = out + (size_t)row * 768;
#pragma unroll
  for (int j = 0; j < 3; ++j) {
    float4 gg = *(const float4*)(g + j * 256 + lane * 4);
    float4 bb = *(const float4*)(b + j * 256 + lane * 4);
    const int base = j * 256 + lane * 4;
    orow[base + 0] = (__bf16)((v[j].x - mu) * rstd * gg.x + bb.x);
    orow[base + 1] = (__bf16)((v[j].y - mu) * rstd * gg.y + bb.y);
    orow[base + 2] = (__bf16)((v[j].z - mu) * rstd * gg.z + bb.z);
    orow[base + 3] = (__bf16)((v[j].w - mu) * rstd * gg.w + bb.w);
  }
}

// ---------------- GEMM: C[M][N] = A[M][K] * BT[N][K]^T + bias (+epilogue) ----------------
template <int MODE>
__global__ __launch_bounds__(256) void k_gemm(const __bf16* __restrict__ A,
                                              const __bf16* __restrict__ BT,
                                              const float* __restrict__ bias,
                                              const float* __restrict__ resid,
                                              void* __restrict__ Cout,
                                              int M, int N, int K) {
  __shared__ __bf16 As[128 * 32];
  __shared__ __bf16 Bs[128 * 32];
  const int m0 = blockIdx.y * 128, n0 = blockIdx.x * 128;
  const int tid = threadIdx.x;
  const int wid = tid >> 6, lane = tid & 63;
  const int wm = wid >> 1, wn = wid & 1;
  const int lr = lane & 15, lg = lane >> 4;

  f32x4 acc[4][4] = {};

  for (int k0 = 0; k0 < K; k0 += 32) {
#pragma unroll
    for (int it = 0; it < 2; ++it) {
      int t = tid + it * 256;
      int r = t >> 2, c = (t & 3) * 8;
      gload_lds16(A + (size_t)(m0 + r) * K + k0 + c, As + t * 8);
      gload_lds16(BT + (size_t)(n0 + r) * K + k0 + c, Bs + t * 8);
    }
    __syncthreads();
    bf16x8 af[4], bf[4];
#pragma unroll
    for (int i = 0; i < 4; ++i) af[i] = *(const bf16x8*)(As + (wm * 64 + i * 16 + lr) * 32 + lg * 8);
#pragma unroll
    for (int j = 0; j < 4; ++j) bf[j] = *(const bf16x8*)(Bs + (wn * 64 + j * 16 + lr) * 32 + lg * 8);
#pragma unroll
    for (int i = 0; i < 4; ++i)
#pragma unroll
      for (int j = 0; j < 4; ++j)
        acc[i][j] = __builtin_amdgcn_mfma_f32_16x16x32_bf16(af[i], bf[j], acc[i][j], 0, 0, 0);
    __syncthreads();
  }

#pragma unroll
  for (int i = 0; i < 4; ++i)
#pragma unroll
    for (int j = 0; j < 4; ++j)
#pragma unroll
      for (int r = 0; r < 4; ++r) {
        int row = m0 + wm * 64 + i * 16 + lg * 4 + r;
        int col = n0 + wn * 64 + j * 16 + lr;
        float v = acc[i][j][r] + bias[col];
        size_t idx = (size_t)row * N + col;
        if constexpr (MODE == 0) {
          ((__bf16*)Cout)[idx] = (__bf16)v;
        } else if constexpr (MODE == 1) {
          ((float*)Cout)[idx] = v + resid[idx];
        } else {
          float gv = 0.5f * v * (1.f + erff(v * 0.70710678118654752f));
          ((__bf16*)Cout)[idx] = (__bf16)gv;
        }
      }
}

// ---------------- pack K into fragment-major KA ----------------
// KA[b][kb][hp][kt][hh][dc][lane][8] = K[b][kb*32 + sig(lane&15) + 4*kt][hp*192+hh*96+dc*32+(lane>>4)*8 + e]
// sig(i) = (i>>2)*8 + (i&3). Reads are 16-row gathers (paid once); writes fully coalesced.
__global__ __launch_bounds__(256) void k_pack_ka(const __bf16* __restrict__ qkv,
                                                 __bf16* __restrict__ KA) {
  const int kb = blockIdx.x, b = blockIdx.y;
  const int t = threadIdx.x;
#pragma unroll
  for (int i = 0; i < 12; ++i) {
    int c = t + i * 256;  // 0..3071
    int lane = c & 63, f = c >> 6;
    int dc = f % 3, hh = (f / 3) & 1, kt = (f / 6) & 1, hp = f / 12;
    int lr = lane & 15;
    int row = kb * 32 + (lr >> 2) * 8 + (lr & 3) + kt * 4;
    int col = 768 + hp * 192 + hh * 96 + dc * 32 + (lane >> 4) * 8;
    bf16x8 v = *(const bf16x8*)(qkv + (size_t)(b * 4096 + row) * 2304 + col);
    *(bf16x8*)(KA + ((size_t)(b * 128 + kb) * 3072 + c) * 8) = v;
  }
}

// ---------------- pack V (transposed) into fragment-major VA ----------------
// VA[b][kb][hp][hh][db][lane][8] = V[b][kb*32 + (lane>>4)*8 + e][hp*192+hh*96+db*16+(lane&15)]
__global__ __launch_bounds__(256) void k_pack_va(const __bf16* __restrict__ qkv,
                                                 __bf16* __restrict__ VA) {
  __shared__ __bf16 vtile[32][772];
  const int kb = blockIdx.x, b = blockIdx.y;
  const int t = threadIdx.x;
#pragma unroll
  for (int i = 0; i < 12; ++i) {
    int c = t + i * 256;
    int row = c / 96, c8 = c % 96;
    *(bf16x8*)(&vtile[row][c8 * 8]) =
        *(const bf16x8*)(qkv + (size_t)(b * 4096 + kb * 32 + row) * 2304 + 1536 + c8 * 8);
  }
  __syncthreads();
#pragma unroll
  for (int i = 0; i < 12; ++i) {
    int c = t + i * 256;
    int lane = c & 63, f = c >> 6;
    int db = f % 6, hh = (f / 6) & 1, hp = f / 12;
    int d = hp * 192 + hh * 96 + db * 16 + (lane & 15);
    int krow = (lane >> 4) * 8;
    bf16x8 v;
#pragma unroll
    for (int e = 0; e < 8; ++e) v[e] = vtile[krow + e][d];
    *(bf16x8*)(VA + ((size_t)(b * 128 + kb) * 3072 + c) * 8) = v;
  }
}

// ---------------- fused attention v4: 2-kb rounds, f32 swizzled psum, b128 exchange ----------------
// grid: 512 linear blocks; slice = bid&7 -> (b, ks) pinned per-XCD; qb = bid>>3.
// 16 waves = (qs 0..3) x (hp 0..3), 64 q-rows, k-range 1024 (16 rounds of 2 kb).
// psum layout: [qs4][kb2][kt2][kslot16][64 f32], inner c = (q*4+hp) ^ ((kslot&7)<<2)
// -> the 4 hp partials for a (q,k) are one aligned 16B quad (b128 read), 4-way banks.
__global__ __launch_bounds__(1024) void k_attn(const __bf16* __restrict__ qkv,
                                               const __bf16* __restrict__ KA,
                                               const __bf16* __restrict__ VA,
                                               __bf16* __restrict__ attn4) {
  __shared__ float psum[16384];  // 64 KB
  const int bid = blockIdx.x;
  const int slice = bid & 7;
  const int b = slice >> 2, ks = slice & 3;
  const int qb = bid >> 3;
  const int wid = threadIdx.x >> 6;
  const int qs = wid & 3, hp = wid >> 2;
  const int q0 = qb * 64 + qs * 16;
  const int lane = threadIdx.x & 63;
  const int lr = lane & 15, lg = lane >> 4;

  // Q fragments (B-operand): lane holds Q row q0+lr, 8 d's (one-time 16-row gather)
  const __bf16* Qb = qkv + (size_t)(b * 4096 + q0) * 2304;
  bf16x8 qf[2][3];
#pragma unroll
  for (int hh = 0; hh < 2; ++hh)
#pragma unroll
    for (int dc = 0; dc < 3; ++dc)
      qf[hh][dc] = *(const bf16x8*)(Qb + (size_t)lr * 2304 + (hp * 2 + hh) * 96 + dc * 32 + lg * 8);

  const int kb0 = ks * 32;
  const __bf16* pK = KA + ((size_t)(b * 128 + kb0) * 4 + hp) * 6144 + lane * 8;
  const __bf16* pV = VA + ((size_t)(b * 128 + kb0) * 4 + hp) * 6144 + lane * 8;

  f32x4 o[2][6] = {};

#define PS_ELEM(kb_, kt_, kslot_, c_) \
  (((((qs * 2 + (kb_)) * 2 + (kt_)) * 16 + (kslot_)) * 64) + (((c_) ^ (((kslot_)&7) << 2))))

  for (int kr = 0; kr < 16; ++kr) {
    f32x4 e[2][2][2] = {};  // [kb][hh][kt]
#pragma unroll
    for (int kb = 0; kb < 2; ++kb)
#pragma unroll
      for (int kt = 0; kt < 2; ++kt)
#pragma unroll
        for (int hh = 0; hh < 2; ++hh)
#pragma unroll
          for (int dc = 0; dc < 3; ++dc) {
            bf16x8 kf = *(const bf16x8*)(pK + kb * 24576 + (kt * 6 + hh * 3 + dc) * 512);
            e[kb][hh][kt] = __builtin_amdgcn_mfma_f32_16x16x32_bf16(kf, qf[hh][dc], e[kb][hh][kt], 0, 0, 0);
          }
    // exp + 2-head partial sums -> f32 psum (swizzled, hp-contiguous quads)
#pragma unroll
    for (int kb = 0; kb < 2; ++kb)
#pragma unroll
      for (int kt = 0; kt < 2; ++kt)
#pragma unroll
        for (int r = 0; r < 4; ++r) {
          float e0 = __expf(e[kb][0][kt][r]);
          float e1 = __expf(e[kb][1][kt][r]);
          e[kb][0][kt][r] = e0;
          e[kb][1][kt][r] = e1;
          psum[PS_ELEM(kb, kt, lg * 4 + r, lr * 4 + hp)] = e0 + e1;
        }
    __syncthreads();
    float inv[2][2][4];
#pragma unroll
    for (int kb = 0; kb < 2; ++kb)
#pragma unroll
      for (int kt = 0; kt < 2; ++kt)
#pragma unroll
        for (int r = 0; r < 4; ++r) {
          f32x4 v = *(const f32x4*)&psum[PS_ELEM(kb, kt, lg * 4 + r, lr * 4)];
          float tot = (v[0] + v[1]) + (v[2] + v[3]);
          inv[kb][kt][r] = 0.03608439182435161f * __builtin_amdgcn_rcpf(tot);
        }
    __syncthreads();
    // P pack + PV per kb
#pragma unroll
    for (int kb = 0; kb < 2; ++kb) {
      bf16x8 pf[2];
#pragma unroll
      for (int hh = 0; hh < 2; ++hh)
#pragma unroll
        for (int e2 = 0; e2 < 8; ++e2) {
          const int kt = e2 >> 2, r = e2 & 3;
          pf[hh][e2] = (__bf16)(e[kb][hh][kt][r] * inv[kb][kt][r]);
        }
#pragma unroll
      for (int hh = 0; hh < 2; ++hh)
#pragma unroll
        for (int db = 0; db < 6; ++db) {
          bf16x8 vf = *(const bf16x8*)(pV + kb * 24576 + (hh * 6 + db) * 512);
          o[hh][db] = __builtin_amdgcn_mfma_f32_16x16x32_bf16(pf[hh], vf, o[hh][db], 0, 0, 0);
        }
    }
    pK += 2 * 24576;
    pV += 2 * 24576;
  }
#undef PS_ELEM

#pragma unroll
  for (int hh = 0; hh < 2; ++hh)
#pragma unroll
    for (int db = 0; db < 6; ++db)
#pragma unroll
      for (int r = 0; r < 4; ++r)
        attn4[(size_t)(b * 4096 + q0 + lg * 4 + r) * 3072 + ks * 768 +
              (hp * 2 + hh) * 96 + db * 16 + lr] = (__bf16)o[hh][db][r];
}

// ---------------- reduce 4 k-split slices -> bf16 ----------------
__global__ __launch_bounds__(256) void k_reduce_attn(const __bf16* __restrict__ attn4,
                                                     __bf16* __restrict__ out) {
  int g = blockIdx.x * 256 + threadIdx.x;  // chunk of 8, total 8192*96
  int row = g / 96, c8 = g % 96;
  const __bf16* p = attn4 + (size_t)row * 3072 + c8 * 8;
  float acc[8] = {};
#pragma unroll
  for (int s = 0; s < 4; ++s) {
    bf16x8 v = *(const bf16x8*)(p + s * 768);
#pragma unroll
    for (int e = 0; e < 8; ++e) acc[e] += (float)v[e];
  }
  bf16x8 r;
#pragma unroll
  for (int e = 0; e < 8; ++e) r[e] = (__bf16)acc[e];
  *(bf16x8*)(out + (size_t)row * 768 + c8 * 8) = r;
}

// ---------------- launcher ----------------
extern "C" void kernel_launch(void* const* d_in, const int* in_sizes, int n_in,
                              void* d_out, int out_size, void* d_ws, size_t ws_size,
                              hipStream_t stream) {
  (void)in_sizes; (void)n_in; (void)out_size; (void)ws_size;
  const float* x     = (const float*)d_in[0];
  const float* ln1_g = (const float*)d_in[1];
  const float* ln1_b = (const float*)d_in[2];
  const float* wq    = (const float*)d_in[3];
  const float* bq    = (const float*)d_in[4];
  const float* wk    = (const float*)d_in[5];
  const float* bk    = (const float*)d_in[6];
  const float* wv    = (const float*)d_in[7];
  const float* bv    = (const float*)d_in[8];
  const float* wp    = (const float*)d_in[9];
  const float* bp    = (const float*)d_in[10];
  const float* ln2_g = (const float*)d_in[11];
  const float* ln2_b = (const float*)d_in[12];
  const float* w1    = (const float*)d_in[13];
  const float* b1    = (const float*)d_in[14];
  const float* w2    = (const float*)d_in[15];
  const float* b2    = (const float*)d_in[16];

  char* ws = (char*)d_ws;
  const size_t o_wqkvT = 0;                                   // [2304][768] bf16
  const size_t o_wpT   = o_wqkvT + (size_t)2304 * 768 * 2;    // [768][768] bf16
  const size_t o_w1T   = o_wpT   + (size_t)768 * 768 * 2;     // [3072][768] bf16
  const size_t o_w2T   = o_w1T   + (size_t)768 * 3072 * 2;    // [768][3072] bf16
  const size_t o_bqkv  = o_w2T   + (size_t)3072 * 768 * 2;    // [2304] f32
  const size_t o_xn    = o_bqkv  + (size_t)2304 * 4;          // [8192][768] bf16
  const size_t o_qkv   = o_xn    + (size_t)8192 * 768 * 2;    // [8192][2304] bf16
  const size_t o_KA    = o_qkv   + (size_t)8192 * 2304 * 2;   // [2][128][3072][8] bf16
  const size_t o_VA    = o_KA    + (size_t)2 * 128 * 3072 * 8 * 2;
  const size_t o_attn4 = o_VA    + (size_t)2 * 128 * 3072 * 8 * 2;  // [8192][3072] bf16
  // aliases (lifetime-disjoint):
  const size_t o_x1      = o_attn4;  // [8192][768] f32 (written after attn4 last read)
  const size_t o_attnred = o_KA;     // [8192][768] bf16 (KA dead after attention)
  const size_t o_xn2     = o_VA;     // [8192][768] bf16 (VA dead after attention)
  const size_t o_hmid    = o_xn;     // [8192][3072] bf16 (spans xn+qkv, both dead)

  __bf16* wqkvT = (__bf16*)(ws + o_wqkvT);
  __bf16* wpT   = (__bf16*)(ws + o_wpT);
  __bf16* w1T   = (__bf16*)(ws + o_w1T);
  __bf16* w2T   = (__bf16*)(ws + o_w2T);
  float*  bqkv  = (float*)(ws + o_bqkv);
  __bf16* xn    = (__bf16*)(ws + o_xn);
  __bf16* qkvb  = (__bf16*)(ws + o_qkv);
  __bf16* KA    = (__bf16*)(ws + o_KA);
  __bf16* VA    = (__bf16*)(ws + o_VA);
  __bf16* attn4 = (__bf16*)(ws + o_attn4);
  float*  x1    = (float*)(ws + o_x1);
  __bf16* attnr = (__bf16*)(ws + o_attnred);
  __bf16* xn2   = (__bf16*)(ws + o_xn2);
  __bf16* hmid  = (__bf16*)(ws + o_hmid);

  dim3 tb(32, 8);
  k_transpose_w<<<dim3(24, 24), tb, 0, stream>>>(wq, wqkvT, 768, 768, 768, 0);
  k_transpose_w<<<dim3(24, 24), tb, 0, stream>>>(wk, wqkvT + (size_t)768 * 768, 768, 768, 768, 0);
  k_transpose_w<<<dim3(24, 24), tb, 0, stream>>>(wv, wqkvT + (size_t)2 * 768 * 768, 768, 768, 768, 0);
  k_transpose_w<<<dim3(24, 24), tb, 0, stream>>>(wp, wpT, 768, 768, 768, 0);
  k_transpose_w<<<dim3(96, 24), tb, 0, stream>>>(w1, w1T, 768, 3072, 768, 0);
  k_transpose_w<<<dim3(24, 96), tb, 0, stream>>>(w2, w2T, 3072, 768, 3072, 0);
  k_pack_bias<<<9, 256, 0, stream>>>(bq, bk, bv, bqkv);

  // LN1 -> xn
  k_layernorm<<<2048, 256, 0, stream>>>(x, ln1_g, ln1_b, xn);
  // QKV projection (fused q|k|v)
  k_gemm<0><<<dim3(18, 64), 256, 0, stream>>>(xn, wqkvT, bqkv, nullptr, qkvb, 8192, 2304, 768);
  // pack K and V into fragment-major layouts
  k_pack_ka<<<dim3(128, 2), 256, 0, stream>>>(qkvb, KA);
  k_pack_va<<<dim3(128, 2), 256, 0, stream>>>(qkvb, VA);
  // attention: 512 blocks x 16 waves, slice pinned per XCD via bid&7
  k_attn<<<512, 1024, 0, stream>>>(qkvb, KA, VA, attn4);
  // sum 4 k-split slices
  k_reduce_attn<<<3072, 256, 0, stream>>>(attn4, attnr);
  // output projection + residual -> x1 (f32)
  k_gemm<1><<<dim3(6, 64), 256, 0, stream>>>(attnr, wpT, bp, x, x1, 8192, 768, 768);
  // LN2 -> xn2
  k_layernorm<<<2048, 256, 0, stream>>>(x1, ln2_g, ln2_b, xn2);
  // MLP1 + exact GELU -> hmid
  k_gemm<2><<<dim3(24, 64), 256, 0, stream>>>(xn2, w1T, b1, nullptr, hmid, 8192, 3072, 768);
  // MLP2 + residual -> out (f32)
  k_gemm<1><<<dim3(6, 64), 256, 0, stream>>>(hmid, w2T, b2, x1, (float*)d_out, 8192, 768, 3072);
}

// Round 5
// 577.434 us; speedup vs baseline: 1.8139x; 1.3064x over previous
//
#include <hip/hip_runtime.h>
#include <cstdint>
#include <cstddef>

#define AS1 __attribute__((address_space(1)))
#define AS3 __attribute__((address_space(3)))

typedef __attribute__((ext_vector_type(8))) __bf16 bf16x8;
typedef __attribute__((ext_vector_type(4))) float f32x4;

__device__ __forceinline__ void gload_lds16(const void* g, void* l) {
  __builtin_amdgcn_global_load_lds((AS1 void*)g, (AS3 void*)l, 16, 0, 0);
}

// lgkm-only barrier: LDS writes drained, global loads stay in flight (no vmcnt(0))
__device__ __forceinline__ void lds_barrier() {
  asm volatile("s_waitcnt lgkmcnt(0)" ::: "memory");
  __builtin_amdgcn_s_barrier();
  asm volatile("" ::: "memory");
}

// ---------------- weight transpose f32 -> bf16 : dst[N][ldd] slice = src[K][N]^T ----------------
__global__ void k_transpose_w(const float* __restrict__ src, __bf16* __restrict__ dst,
                              int K, int N, int ldd, int koff) {
  __shared__ float tile[32][33];
  const int bx = blockIdx.x * 32;  // N dim
  const int by = blockIdx.y * 32;  // K dim
  const int tx = threadIdx.x, ty = threadIdx.y;
#pragma unroll
  for (int ii = 0; ii < 4; ++ii) {
    int i = ty + ii * 8;
    tile[i][tx] = src[(size_t)(by + i) * N + bx + tx];
  }
  __syncthreads();
#pragma unroll
  for (int ii = 0; ii < 4; ++ii) {
    int i = ty + ii * 8;
    dst[(size_t)(bx + i) * ldd + koff + by + tx] = (__bf16)tile[tx][i];
  }
}

// ---------------- pack qkv bias ----------------
__global__ void k_pack_bias(const float* __restrict__ bq, const float* __restrict__ bk,
                            const float* __restrict__ bv, float* __restrict__ dst) {
  int i = blockIdx.x * 256 + threadIdx.x;
  if (i < 768) dst[i] = bq[i];
  else if (i < 1536) dst[i] = bk[i - 768];
  else if (i < 2304) dst[i] = bv[i - 1536];
}

// ---------------- LayerNorm f32 -> bf16 (one wave per 768-row) ----------------
__global__ __launch_bounds__(256) void k_layernorm(const float* __restrict__ x,
                                                   const float* __restrict__ g,
                                                   const float* __restrict__ b,
                                                   __bf16* __restrict__ out) {
  const int row = blockIdx.x * 4 + (threadIdx.x >> 6);
  const int lane = threadIdx.x & 63;
  const float* xr = x + (size_t)row * 768;
  float4 v[3];
#pragma unroll
  for (int j = 0; j < 3; ++j) v[j] = *(const float4*)(xr + j * 256 + lane * 4);
  float s = 0.f, ss = 0.f;
#pragma unroll
  for (int j = 0; j < 3; ++j) {
    s += v[j].x + v[j].y + v[j].z + v[j].w;
    ss += v[j].x * v[j].x + v[j].y * v[j].y + v[j].z * v[j].z + v[j].w * v[j].w;
  }
#pragma unroll
  for (int off = 32; off > 0; off >>= 1) {
    s += __shfl_xor(s, off);
    ss += __shfl_xor(ss, off);
  }
  const float mu = s * (1.f / 768.f);
  const float rstd = rsqrtf(ss * (1.f / 768.f) - mu * mu + 1e-5f);
  __bf16* orow = out + (size_t)row * 768;
#pragma unroll
  for (int j = 0; j < 3; ++j) {
    float4 gg = *(const float4*)(g + j * 256 + lane * 4);
    float4 bb = *(const float4*)(b + j * 256 + lane * 4);
    const int base = j * 256 + lane * 4;
    orow[base + 0] = (__bf16)((v[j].x - mu) * rstd * gg.x + bb.x);
    orow[base + 1] = (__bf16)((v[j].y - mu) * rstd * gg.y + bb.y);
    orow[base + 2] = (__bf16)((v[j].z - mu) * rstd * gg.z + bb.z);
    orow[base + 3] = (__bf16)((v[j].w - mu) * rstd * gg.w + bb.w);
  }
}

// ---------------- GEMM: C[M][N] = A[M][K] * BT[N][K]^T + bias (+epilogue) ----------------
template <int MODE>
__global__ __launch_bounds__(256) void k_gemm(const __bf16* __restrict__ A,
                                              const __bf16* __restrict__ BT,
                                              const float* __restrict__ bias,
                                              const float* __restrict__ resid,
                                              void* __restrict__ Cout,
                                              int M, int N, int K) {
  __shared__ __bf16 As[128 * 32];
  __shared__ __bf16 Bs[128 * 32];
  const int m0 = blockIdx.y * 128, n0 = blockIdx.x * 128;
  const int tid = threadIdx.x;
  const int wid = tid >> 6, lane = tid & 63;
  const int wm = wid >> 1, wn = wid & 1;
  const int lr = lane & 15, lg = lane >> 4;

  f32x4 acc[4][4] = {};

  for (int k0 = 0; k0 < K; k0 += 32) {
#pragma unroll
    for (int it = 0; it < 2; ++it) {
      int t = tid + it * 256;
      int r = t >> 2, c = (t & 3) * 8;
      gload_lds16(A + (size_t)(m0 + r) * K + k0 + c, As + t * 8);
      gload_lds16(BT + (size_t)(n0 + r) * K + k0 + c, Bs + t * 8);
    }
    __syncthreads();
    bf16x8 af[4], bf[4];
#pragma unroll
    for (int i = 0; i < 4; ++i) af[i] = *(const bf16x8*)(As + (wm * 64 + i * 16 + lr) * 32 + lg * 8);
#pragma unroll
    for (int j = 0; j < 4; ++j) bf[j] = *(const bf16x8*)(Bs + (wn * 64 + j * 16 + lr) * 32 + lg * 8);
#pragma unroll
    for (int i = 0; i < 4; ++i)
#pragma unroll
      for (int j = 0; j < 4; ++j)
        acc[i][j] = __builtin_amdgcn_mfma_f32_16x16x32_bf16(af[i], bf[j], acc[i][j], 0, 0, 0);
    __syncthreads();
  }

#pragma unroll
  for (int i = 0; i < 4; ++i)
#pragma unroll
    for (int j = 0; j < 4; ++j)
#pragma unroll
      for (int r = 0; r < 4; ++r) {
        int row = m0 + wm * 64 + i * 16 + lg * 4 + r;
        int col = n0 + wn * 64 + j * 16 + lr;
        float v = acc[i][j][r] + bias[col];
        size_t idx = (size_t)row * N + col;
        if constexpr (MODE == 0) {
          ((__bf16*)Cout)[idx] = (__bf16)v;
        } else if constexpr (MODE == 1) {
          ((float*)Cout)[idx] = v + resid[idx];
        } else {
          float gv = 0.5f * v * (1.f + erff(v * 0.70710678118654752f));
          ((__bf16*)Cout)[idx] = (__bf16)gv;
        }
      }
}

// ---------------- pack K into fragment-major KA ----------------
// KA[b][kb][hp][kt][hh][dc][lane][8] = K[b][kb*32 + sig(lane&15) + 4*kt][hp*192+hh*96+dc*32+(lane>>4)*8 + e]
// sig(i) = (i>>2)*8 + (i&3). Reads are 16-row gathers (paid once); writes fully coalesced.
__global__ __launch_bounds__(256) void k_pack_ka(const __bf16* __restrict__ qkv,
                                                 __bf16* __restrict__ KA) {
  const int kb = blockIdx.x, b = blockIdx.y;
  const int t = threadIdx.x;
#pragma unroll
  for (int i = 0; i < 12; ++i) {
    int c = t + i * 256;  // 0..3071
    int lane = c & 63, f = c >> 6;
    int dc = f % 3, hh = (f / 3) & 1, kt = (f / 6) & 1, hp = f / 12;
    int lr = lane & 15;
    int row = kb * 32 + (lr >> 2) * 8 + (lr & 3) + kt * 4;
    int col = 768 + hp * 192 + hh * 96 + dc * 32 + (lane >> 4) * 8;
    bf16x8 v = *(const bf16x8*)(qkv + (size_t)(b * 4096 + row) * 2304 + col);
    *(bf16x8*)(KA + ((size_t)(b * 128 + kb) * 3072 + c) * 8) = v;
  }
}

// ---------------- pack V (transposed) into fragment-major VA ----------------
// VA[b][kb][hp][hh][db][lane][8] = V[b][kb*32 + (lane>>4)*8 + e][hp*192+hh*96+db*16+(lane&15)]
__global__ __launch_bounds__(256) void k_pack_va(const __bf16* __restrict__ qkv,
                                                 __bf16* __restrict__ VA) {
  __shared__ __bf16 vtile[32][772];
  const int kb = blockIdx.x, b = blockIdx.y;
  const int t = threadIdx.x;
#pragma unroll
  for (int i = 0; i < 12; ++i) {
    int c = t + i * 256;
    int row = c / 96, c8 = c % 96;
    *(bf16x8*)(&vtile[row][c8 * 8]) =
        *(const bf16x8*)(qkv + (size_t)(b * 4096 + kb * 32 + row) * 2304 + 1536 + c8 * 8);
  }
  __syncthreads();
#pragma unroll
  for (int i = 0; i < 12; ++i) {
    int c = t + i * 256;
    int lane = c & 63, f = c >> 6;
    int db = f % 6, hh = (f / 6) & 1, hp = f / 12;
    int d = hp * 192 + hh * 96 + db * 16 + (lane & 15);
    int krow = (lane >> 4) * 8;
    bf16x8 v;
#pragma unroll
    for (int e = 0; e < 8; ++e) v[e] = vtile[krow + e][d];
    *(bf16x8*)(VA + ((size_t)(b * 128 + kb) * 3072 + c) * 8) = v;
  }
}

// ---------------- fused attention v5: 4-wave blocks, lgkm-only barrier, ping-pong psum -------
// grid 2048: slice = bid&7 -> (b,ks) per-XCD; qt = bid>>3 -> 16 q-rows.
// 4 waves = head-pairs hp 0..3. 32 rounds of 32 k, ONE lgkm-only barrier each.
// psum[2 buf][kt2][kslot16][hp4][17] f32: write bank = 16*lg+lr (+const) -> 2-way (free);
// read 4 scalars per total, same banks. Global K/V loads never drained at barriers.
__global__ __launch_bounds__(256, 4) void k_attn(const __bf16* __restrict__ qkv,
                                                 const __bf16* __restrict__ KA,
                                                 const __bf16* __restrict__ VA,
                                                 __bf16* __restrict__ attn4) {
  __shared__ float psum[2 * 2176];  // 2 x [2][16][4][17] f32 = 17.4 KB
  const int bid = blockIdx.x;
  const int slice = bid & 7;
  const int b = slice >> 2, ks = slice & 3;
  const int q0 = (bid >> 3) * 16;
  const int hp = threadIdx.x >> 6;
  const int lane = threadIdx.x & 63;
  const int lr = lane & 15, lg = lane >> 4;

  // Q fragments (B-operand): lane holds Q row q0+lr, 8 d's (one-time 16-row gather)
  const __bf16* Qb = qkv + (size_t)(b * 4096 + q0) * 2304;
  bf16x8 qf[2][3];
#pragma unroll
  for (int hh = 0; hh < 2; ++hh)
#pragma unroll
    for (int dc = 0; dc < 3; ++dc)
      qf[hh][dc] = *(const bf16x8*)(Qb + (size_t)lr * 2304 + (hp * 2 + hh) * 96 + dc * 32 + lg * 8);

  const int kb0 = ks * 32;
  const __bf16* pK = KA + ((size_t)(b * 128 + kb0) * 4 + hp) * 6144 + lane * 8;
  const __bf16* pV = VA + ((size_t)(b * 128 + kb0) * 4 + hp) * 6144 + lane * 8;

  f32x4 o[2][6] = {};

  for (int r = 0; r < 32; ++r) {
    const int wb = (r & 1) * 2176;
    f32x4 e[2][2] = {};  // [hh][kt]
    __builtin_amdgcn_s_setprio(1);
#pragma unroll
    for (int kt = 0; kt < 2; ++kt)
#pragma unroll
      for (int hh = 0; hh < 2; ++hh)
#pragma unroll
        for (int dc = 0; dc < 3; ++dc) {
          bf16x8 kf = *(const bf16x8*)(pK + (kt * 6 + hh * 3 + dc) * 512);
          e[hh][kt] = __builtin_amdgcn_mfma_f32_16x16x32_bf16(kf, qf[hh][dc], e[hh][kt], 0, 0, 0);
        }
    __builtin_amdgcn_s_setprio(0);
    // exp + 2-head partial sums -> psum[wb]
#pragma unroll
    for (int kt = 0; kt < 2; ++kt)
#pragma unroll
      for (int rr = 0; rr < 4; ++rr) {
        float e0 = __expf(e[0][kt][rr]);
        float e1 = __expf(e[1][kt][rr]);
        e[0][kt][rr] = e0;
        e[1][kt][rr] = e1;
        psum[wb + kt * 1088 + (lg * 4 + rr) * 68 + hp * 17 + lr] = e0 + e1;
      }
    lds_barrier();
    float inv[2][4];
#pragma unroll
    for (int kt = 0; kt < 2; ++kt)
#pragma unroll
      for (int rr = 0; rr < 4; ++rr) {
        const int base = wb + kt * 1088 + (lg * 4 + rr) * 68 + lr;
        float tot = (psum[base] + psum[base + 17]) + (psum[base + 34] + psum[base + 51]);
        inv[kt][rr] = 0.03608439182435161f * __builtin_amdgcn_rcpf(tot);
      }
    // P pack + PV
    bf16x8 pf[2];
#pragma unroll
    for (int hh = 0; hh < 2; ++hh)
#pragma unroll
      for (int e2 = 0; e2 < 8; ++e2) {
        const int kt = e2 >> 2, rr = e2 & 3;
        pf[hh][e2] = (__bf16)(e[hh][kt][rr] * inv[kt][rr]);
      }
    __builtin_amdgcn_s_setprio(1);
#pragma unroll
    for (int hh = 0; hh < 2; ++hh)
#pragma unroll
      for (int db = 0; db < 6; ++db) {
        bf16x8 vf = *(const bf16x8*)(pV + (hh * 6 + db) * 512);
        o[hh][db] = __builtin_amdgcn_mfma_f32_16x16x32_bf16(pf[hh], vf, o[hh][db], 0, 0, 0);
      }
    __builtin_amdgcn_s_setprio(0);
    pK += 24576;
    pV += 24576;
  }

#pragma unroll
  for (int hh = 0; hh < 2; ++hh)
#pragma unroll
    for (int db = 0; db < 6; ++db)
#pragma unroll
      for (int rr = 0; rr < 4; ++rr)
        attn4[(size_t)(b * 4096 + q0 + lg * 4 + rr) * 3072 + ks * 768 +
              (hp * 2 + hh) * 96 + db * 16 + lr] = (__bf16)o[hh][db][rr];
}

// ---------------- reduce 4 k-split slices -> bf16 ----------------
__global__ __launch_bounds__(256) void k_reduce_attn(const __bf16* __restrict__ attn4,
                                                     __bf16* __restrict__ out) {
  int g = blockIdx.x * 256 + threadIdx.x;  // chunk of 8, total 8192*96
  int row = g / 96, c8 = g % 96;
  const __bf16* p = attn4 + (size_t)row * 3072 + c8 * 8;
  float acc[8] = {};
#pragma unroll
  for (int s = 0; s < 4; ++s) {
    bf16x8 v = *(const bf16x8*)(p + s * 768);
#pragma unroll
    for (int e = 0; e < 8; ++e) acc[e] += (float)v[e];
  }
  bf16x8 r;
#pragma unroll
  for (int e = 0; e < 8; ++e) r[e] = (__bf16)acc[e];
  *(bf16x8*)(out + (size_t)row * 768 + c8 * 8) = r;
}

// ---------------- launcher ----------------
extern "C" void kernel_launch(void* const* d_in, const int* in_sizes, int n_in,
                              void* d_out, int out_size, void* d_ws, size_t ws_size,
                              hipStream_t stream) {
  (void)in_sizes; (void)n_in; (void)out_size; (void)ws_size;
  const float* x     = (const float*)d_in[0];
  const float* ln1_g = (const float*)d_in[1];
  const float* ln1_b = (const float*)d_in[2];
  const float* wq    = (const float*)d_in[3];
  const float* bq    = (const float*)d_in[4];
  const float* wk    = (const float*)d_in[5];
  const float* bk    = (const float*)d_in[6];
  const float* wv    = (const float*)d_in[7];
  const float* bv    = (const float*)d_in[8];
  const float* wp    = (const float*)d_in[9];
  const float* bp    = (const float*)d_in[10];
  const float* ln2_g = (const float*)d_in[11];
  const float* ln2_b = (const float*)d_in[12];
  const float* w1    = (const float*)d_in[13];
  const float* b1    = (const float*)d_in[14];
  const float* w2    = (const float*)d_in[15];
  const float* b2    = (const float*)d_in[16];

  char* ws = (char*)d_ws;
  const size_t o_wqkvT = 0;                                   // [2304][768] bf16
  const size_t o_wpT   = o_wqkvT + (size_t)2304 * 768 * 2;    // [768][768] bf16
  const size_t o_w1T   = o_wpT   + (size_t)768 * 768 * 2;     // [3072][768] bf16
  const size_t o_w2T   = o_w1T   + (size_t)768 * 3072 * 2;    // [768][3072] bf16
  const size_t o_bqkv  = o_w2T   + (size_t)3072 * 768 * 2;    // [2304] f32
  const size_t o_xn    = o_bqkv  + (size_t)2304 * 4;          // [8192][768] bf16
  const size_t o_qkv   = o_xn    + (size_t)8192 * 768 * 2;    // [8192][2304] bf16
  const size_t o_KA    = o_qkv   + (size_t)8192 * 2304 * 2;   // [2][128][3072][8] bf16
  const size_t o_VA    = o_KA    + (size_t)2 * 128 * 3072 * 8 * 2;
  const size_t o_attn4 = o_VA    + (size_t)2 * 128 * 3072 * 8 * 2;  // [8192][3072] bf16
  // aliases (lifetime-disjoint):
  const size_t o_x1      = o_attn4;  // [8192][768] f32 (written after attn4 last read)
  const size_t o_attnred = o_KA;     // [8192][768] bf16 (KA dead after attention)
  const size_t o_xn2     = o_VA;     // [8192][768] bf16 (VA dead after attention)
  const size_t o_hmid    = o_xn;     // [8192][3072] bf16 (spans xn+qkv, both dead)

  __bf16* wqkvT = (__bf16*)(ws + o_wqkvT);
  __bf16* wpT   = (__bf16*)(ws + o_wpT);
  __bf16* w1T   = (__bf16*)(ws + o_w1T);
  __bf16* w2T   = (__bf16*)(ws + o_w2T);
  float*  bqkv  = (float*)(ws + o_bqkv);
  __bf16* xn    = (__bf16*)(ws + o_xn);
  __bf16* qkvb  = (__bf16*)(ws + o_qkv);
  __bf16* KA    = (__bf16*)(ws + o_KA);
  __bf16* VA    = (__bf16*)(ws + o_VA);
  __bf16* attn4 = (__bf16*)(ws + o_attn4);
  float*  x1    = (float*)(ws + o_x1);
  __bf16* attnr = (__bf16*)(ws + o_attnred);
  __bf16* xn2   = (__bf16*)(ws + o_xn2);
  __bf16* hmid  = (__bf16*)(ws + o_hmid);

  dim3 tb(32, 8);
  k_transpose_w<<<dim3(24, 24), tb, 0, stream>>>(wq, wqkvT, 768, 768, 768, 0);
  k_transpose_w<<<dim3(24, 24), tb, 0, stream>>>(wk, wqkvT + (size_t)768 * 768, 768, 768, 768, 0);
  k_transpose_w<<<dim3(24, 24), tb, 0, stream>>>(wv, wqkvT + (size_t)2 * 768 * 768, 768, 768, 768, 0);
  k_transpose_w<<<dim3(24, 24), tb, 0, stream>>>(wp, wpT, 768, 768, 768, 0);
  k_transpose_w<<<dim3(96, 24), tb, 0, stream>>>(w1, w1T, 768, 3072, 768, 0);
  k_transpose_w<<<dim3(24, 96), tb, 0, stream>>>(w2, w2T, 3072, 768, 3072, 0);
  k_pack_bias<<<9, 256, 0, stream>>>(bq, bk, bv, bqkv);

  // LN1 -> xn
  k_layernorm<<<2048, 256, 0, stream>>>(x, ln1_g, ln1_b, xn);
  // QKV projection (fused q|k|v)
  k_gemm<0><<<dim3(18, 64), 256, 0, stream>>>(xn, wqkvT, bqkv, nullptr, qkvb, 8192, 2304, 768);
  // pack K and V into fragment-major layouts
  k_pack_ka<<<dim3(128, 2), 256, 0, stream>>>(qkvb, KA);
  k_pack_va<<<dim3(128, 2), 256, 0, stream>>>(qkvb, VA);
  // attention: 2048 blocks x 4 waves, slice pinned per XCD via bid&7
  k_attn<<<2048, 256, 0, stream>>>(qkvb, KA, VA, attn4);
  // sum 4 k-split slices
  k_reduce_attn<<<3072, 256, 0, stream>>>(attn4, attnr);
  // output projection + residual -> x1 (f32)
  k_gemm<1><<<dim3(6, 64), 256, 0, stream>>>(attnr, wpT, bp, x, x1, 8192, 768, 768);
  // LN2 -> xn2
  k_layernorm<<<2048, 256, 0, stream>>>(x1, ln2_g, ln2_b, xn2);
  // MLP1 + exact GELU -> hmid
  k_gemm<2><<<dim3(24, 64), 256, 0, stream>>>(xn2, w1T, b1, nullptr, hmid, 8192, 3072, 768);
  // MLP2 + residual -> out (f32)
  k_gemm<1><<<dim3(6, 64), 256, 0, stream>>>(hmid, w2T, b2, x1, (float*)d_out, 8192, 768, 3072);
}